// Round 1
// baseline (1291.586 us; speedup 1.0000x reference)
//
#include <hip/hip_runtime.h>

#define B_SZ 262144
#define D_SZ 256
#define C_SZ 100000
#define ROWS_PER_BLOCK 4
#define LOSS_SLOTS 1024

// ws layout: [0, 8192)   : 1024 double loss slots
//            [8192, ...) : C_SZ float counts
__global__ void __launch_bounds__(256)
center_loss_main(const float* __restrict__ features,
                 const int* __restrict__ labels,
                 const float* __restrict__ centers,
                 float* __restrict__ update,      // d_out+1 (zeroed), scatter acc
                 float* __restrict__ counts,      // ws, zeroed
                 double* __restrict__ loss_slots) // ws, zeroed
{
    const int tid  = threadIdx.x;
    const int rib  = tid >> 6;        // row within block 0..3
    const int lane = tid & 63;
    const long row = (long)blockIdx.x * ROWS_PER_BLOCK + rib;

    const int label = labels[row];
    const long foff = row * D_SZ + (long)lane * 4;
    const long coff = (long)label * D_SZ + (long)lane * 4;

    const float4 f = *(const float4*)(features + foff);
    const float4 c = *(const float4*)(centers + coff);

    const float dx = c.x - f.x;
    const float dy = c.y - f.y;
    const float dz = c.z - f.z;
    const float dw = c.w - f.w;

    // scatter-add diff into per-class update accumulator
    atomicAdd(update + coff + 0, dx);
    atomicAdd(update + coff + 1, dy);
    atomicAdd(update + coff + 2, dz);
    atomicAdd(update + coff + 3, dw);

    if (lane == 0) atomicAdd(counts + label, 1.0f);

    // loss partial: sum of squares
    float local = dx * dx + dy * dy + dz * dz + dw * dw;
    #pragma unroll
    for (int off = 32; off > 0; off >>= 1)
        local += __shfl_down(local, off, 64);

    __shared__ float partial[ROWS_PER_BLOCK];
    if (lane == 0) partial[rib] = local;
    __syncthreads();
    if (tid == 0) {
        float s = partial[0] + partial[1] + partial[2] + partial[3];
        atomicAdd(loss_slots + (blockIdx.x & (LOSS_SLOTS - 1)), (double)s);
    }
}

__global__ void __launch_bounds__(256)
loss_finalize(const double* __restrict__ slots, float* __restrict__ out0)
{
    const int tid = threadIdx.x;
    double s = slots[tid] + slots[tid + 256] + slots[tid + 512] + slots[tid + 768];
    #pragma unroll
    for (int off = 32; off > 0; off >>= 1)
        s += __shfl_down(s, off, 64);

    __shared__ double ps[4];
    if ((tid & 63) == 0) ps[tid >> 6] = s;
    __syncthreads();
    if (tid == 0) {
        double tot = ps[0] + ps[1] + ps[2] + ps[3];
        *out0 = (float)(tot / 2.0 / (double)B_SZ);
    }
}

__global__ void __launch_bounds__(256)
center_finalize(const float* __restrict__ centers,
                const float* __restrict__ counts,
                float* __restrict__ out_centers) // d_out+1: holds update, becomes new_centers
{
    const long idx = ((long)blockIdx.x * 256 + threadIdx.x) * 4;
    if (idx >= (long)C_SZ * D_SZ) return;
    const int cls = (int)(idx >> 8);            // /D_SZ
    const float cnt = counts[cls] + 1.0f;
    #pragma unroll
    for (int k = 0; k < 4; k++) {
        const float u = out_centers[idx + k];
        out_centers[idx + k] = centers[idx + k] - u / cnt;
    }
}

extern "C" void kernel_launch(void* const* d_in, const int* in_sizes, int n_in,
                              void* d_out, int out_size, void* d_ws, size_t ws_size,
                              hipStream_t stream) {
    const float* features = (const float*)d_in[0];
    const int*   labels   = (const int*)d_in[1];
    const float* centers  = (const float*)d_in[2];

    float*  out      = (float*)d_out;           // out[0]=loss, out[1..]=new_centers
    double* lslots   = (double*)d_ws;
    float*  counts   = (float*)((char*)d_ws + LOSS_SLOTS * sizeof(double));

    // zero accumulators (harness re-poisons d_out/d_ws with 0xAA before every call)
    hipMemsetAsync(d_out, 0, (size_t)(1 + (long)C_SZ * D_SZ) * sizeof(float), stream);
    hipMemsetAsync(d_ws, 0, LOSS_SLOTS * sizeof(double) + (size_t)C_SZ * sizeof(float), stream);

    // main scatter pass
    center_loss_main<<<B_SZ / ROWS_PER_BLOCK, 256, 0, stream>>>(
        features, labels, centers, out + 1, counts, lslots);

    // finalize
    loss_finalize<<<1, 256, 0, stream>>>(lslots, out);
    const long cd = (long)C_SZ * D_SZ;                 // 25,600,000 (divisible by 4)
    center_finalize<<<(cd / 4 + 255) / 256, 256, 0, stream>>>(centers, counts, out + 1);
}

// Round 2
// 507.781 us; speedup vs baseline: 2.5436x; 2.5436x over previous
//
#include <hip/hip_runtime.h>

#define B_SZ 262144
#define D_SZ 256
#define C_SZ 100000
#define LOSS_SLOTS 1024

// ws layout (bytes):
//   [0,       8192)    loss_slots: 1024 doubles
//   [8192,    408192)  counts:     100000 int
//   [408192,  408196)  cursor:     1 int
//   [408200,  808200)  start:      100000 int
//   [808200, 1208200)  fill:       100000 int
//   [1208200,2256776)  rowidx:     262144 int
#define OFF_COUNTS  8192
#define OFF_CURSOR  408192
#define OFF_START   408200
#define OFF_FILL    808200
#define OFF_ROWIDX  1208200
#define ZERO_BYTES  408196   // slots + counts + cursor

__global__ void __launch_bounds__(256)
hist_kernel(const int* __restrict__ labels, int* __restrict__ counts)
{
    const int i = blockIdx.x * 256 + threadIdx.x;
    atomicAdd(counts + labels[i], 1);
}

__global__ void __launch_bounds__(256)
assign_segments(const int* __restrict__ counts, int* __restrict__ start,
                int* __restrict__ fill, int* __restrict__ cursor)
{
    const int c = blockIdx.x * 256 + threadIdx.x;
    const int lane = threadIdx.x & 63;
    const int n = (c < C_SZ) ? counts[c] : 0;
    // wave-inclusive scan
    int inc = n;
    #pragma unroll
    for (int off = 1; off < 64; off <<= 1) {
        int t = __shfl_up(inc, off, 64);
        if (lane >= off) inc += t;
    }
    const int total = __shfl(inc, 63, 64);
    int base = 0;
    if (lane == 63) base = atomicAdd(cursor, total);
    base = __shfl(base, 63, 64);
    if (c < C_SZ) {
        const int s = base + inc - n;   // exclusive within wave + global base
        start[c] = s;
        fill[c]  = s;
    }
}

__global__ void __launch_bounds__(256)
scatter_rows(const int* __restrict__ labels, int* __restrict__ fill,
             int* __restrict__ rowidx)
{
    const int i = blockIdx.x * 256 + threadIdx.x;
    const int lab = labels[i];
    const int pos = atomicAdd(fill + lab, 1);
    rowidx[pos] = i;
}

// one wave per class; lane l owns dims [4l, 4l+4)
__global__ void __launch_bounds__(256)
class_reduce(const float* __restrict__ features,
             const float* __restrict__ centers,
             const int* __restrict__ counts,
             const int* __restrict__ start,
             const int* __restrict__ rowidx,
             float* __restrict__ out_centers,   // d_out + 1 (NOT 16B-aligned)
             double* __restrict__ loss_slots)
{
    const int tid  = threadIdx.x;
    const int lane = tid & 63;
    const int c    = blockIdx.x * 4 + (tid >> 6);   // 25000*4 == C_SZ exactly
    const long cbase = (long)c * D_SZ + (long)lane * 4;

    const float4 cv = *(const float4*)(centers + cbase);
    const int cnt = counts[c];
    const int s   = start[c];

    float4 sf = make_float4(0.f, 0.f, 0.f, 0.f);
    float loss = 0.f;
    for (int j = 0; j < cnt; ++j) {
        const int r = rowidx[s + j];                 // wave-uniform, L1 broadcast
        const float4 f = *(const float4*)(features + (long)r * D_SZ + (long)lane * 4);
        sf.x += f.x; sf.y += f.y; sf.z += f.z; sf.w += f.w;
        const float dx = f.x - cv.x, dy = f.y - cv.y;
        const float dz = f.z - cv.z, dw = f.w - cv.w;
        loss += dx * dx + dy * dy + dz * dz + dw * dw;
    }

    const float denom = (float)(cnt + 1);
    const float fc = (float)cnt;
    float* o = out_centers + cbase;                  // 4 scalar stores (base +4B misaligned)
    o[0] = cv.x - (fc * cv.x - sf.x) / denom;
    o[1] = cv.y - (fc * cv.y - sf.y) / denom;
    o[2] = cv.z - (fc * cv.z - sf.z) / denom;
    o[3] = cv.w - (fc * cv.w - sf.w) / denom;

    #pragma unroll
    for (int off = 32; off > 0; off >>= 1)
        loss += __shfl_down(loss, off, 64);
    if (lane == 0)
        atomicAdd(loss_slots + (c & (LOSS_SLOTS - 1)), (double)loss);
}

__global__ void __launch_bounds__(256)
loss_finalize(const double* __restrict__ slots, float* __restrict__ out0)
{
    const int tid = threadIdx.x;
    double s = slots[tid] + slots[tid + 256] + slots[tid + 512] + slots[tid + 768];
    #pragma unroll
    for (int off = 32; off > 0; off >>= 1)
        s += __shfl_down(s, off, 64);

    __shared__ double ps[4];
    if ((tid & 63) == 0) ps[tid >> 6] = s;
    __syncthreads();
    if (tid == 0) {
        const double tot = ps[0] + ps[1] + ps[2] + ps[3];
        *out0 = (float)(tot / 2.0 / (double)B_SZ);
    }
}

extern "C" void kernel_launch(void* const* d_in, const int* in_sizes, int n_in,
                              void* d_out, int out_size, void* d_ws, size_t ws_size,
                              hipStream_t stream) {
    const float* features = (const float*)d_in[0];
    const int*   labels   = (const int*)d_in[1];
    const float* centers  = (const float*)d_in[2];

    float* out = (float*)d_out;                  // out[0]=loss, out[1..]=new_centers
    char*  ws  = (char*)d_ws;
    double* lslots = (double*)ws;
    int* counts = (int*)(ws + OFF_COUNTS);
    int* cursor = (int*)(ws + OFF_CURSOR);
    int* start  = (int*)(ws + OFF_START);
    int* fill   = (int*)(ws + OFF_FILL);
    int* rowidx = (int*)(ws + OFF_ROWIDX);

    hipMemsetAsync(d_ws, 0, ZERO_BYTES, stream);

    hist_kernel<<<B_SZ / 256, 256, 0, stream>>>(labels, counts);
    assign_segments<<<(C_SZ + 255) / 256, 256, 0, stream>>>(counts, start, fill, cursor);
    scatter_rows<<<B_SZ / 256, 256, 0, stream>>>(labels, fill, rowidx);
    class_reduce<<<C_SZ / 4, 256, 0, stream>>>(features, centers, counts, start,
                                               rowidx, out + 1, lslots);
    loss_finalize<<<1, 256, 0, stream>>>(lslots, out);
}